// Round 5
// baseline (754.354 us; speedup 1.0000x reference)
//
#include <hip/hip_runtime.h>
#include <math.h>

typedef __bf16 bf16_t;
typedef __bf16 bf16x2 __attribute__((ext_vector_type(2)));
typedef __bf16 bf16x4 __attribute__((ext_vector_type(4)));
typedef __bf16 bf16x8 __attribute__((ext_vector_type(8)));
typedef float f32x4 __attribute__((ext_vector_type(4)));

#define B_ 2
#define S_ 2048
#define D_ 1024
#define NH 16
#define HD 64
#define FF 4096
#define NTOK (B_*S_)   // 4096 rows

__device__ __forceinline__ f32x4 mfma16(bf16x8 a, bf16x8 b, f32x4 c) {
  return __builtin_amdgcn_mfma_f32_16x16x32_bf16(a, b, c, 0, 0, 0);
}

__device__ __forceinline__ void gld_lds16(const bf16_t* g, bf16_t* l) {
  __builtin_amdgcn_global_load_lds(
      (const __attribute__((address_space(1))) void*)g,
      (__attribute__((address_space(3))) void*)l, 16, 0, 0);
}

// ---------------- fp32 -> bf16 convert ----------------
__global__ __launch_bounds__(256) void cvt_kernel(const float* __restrict__ in,
                                                  bf16_t* __restrict__ o, int n4) {
  int i = blockIdx.x * 256 + threadIdx.x;
  const int stride = gridDim.x * 256;
  for (; i < n4; i += stride) {
    float4 v = ((const float4*)in)[i];
    bf16x4 ov;
    ov[0] = (bf16_t)v.x; ov[1] = (bf16_t)v.y; ov[2] = (bf16_t)v.z; ov[3] = (bf16_t)v.w;
    ((bf16x4*)o)[i] = ov;
  }
}

// ---------------- RMSNorm (fp32 in, bf16 out) ----------------
__global__ __launch_bounds__(256) void rmsnorm_kernel(const float* __restrict__ x,
                                                      const float* __restrict__ w,
                                                      bf16_t* __restrict__ o) {
  const int row = blockIdx.x;
  const float4 v = ((const float4*)(x + (size_t)row * D_))[threadIdx.x];
  float s = v.x*v.x + v.y*v.y + v.z*v.z + v.w*v.w;
  #pragma unroll
  for (int d = 32; d; d >>= 1) s += __shfl_down(s, d);
  __shared__ float acc[4];
  if ((threadIdx.x & 63) == 0) acc[threadIdx.x >> 6] = s;
  __syncthreads();
  const float scale = rsqrtf((acc[0] + acc[1] + acc[2] + acc[3]) * (1.f / D_) + 1e-6f);
  const float4 wv = ((const float4*)w)[threadIdx.x];
  bf16x4 ov;
  ov[0] = (bf16_t)(v.x * scale * wv.x);
  ov[1] = (bf16_t)(v.y * scale * wv.y);
  ov[2] = (bf16_t)(v.z * scale * wv.z);
  ov[3] = (bf16_t)(v.w * scale * wv.w);
  ((bf16x4*)(o + (size_t)row * D_))[threadIdx.x] = ov;
}

// ---------------- GEMM: C(MxN) = A(MxK,bf16) @ W(NxK,bf16)^T ----------------
// BM=128 fixed; BN in {64,128}. 4 waves.
// BN=128: wave grid 2x2, each 64x64 (acc 4x4). BN=64: wave grid 2x2, each 64x32.
template<int MODE, int BN>
__global__ __launch_bounds__(256) void gemm_kernel(
    const bf16_t* __restrict__ A, const bf16_t* __restrict__ W,
    int M, int N, int K,
    float* __restrict__ outF, bf16_t* __restrict__ outB,
    const float* __restrict__ res, const bf16_t* __restrict__ gate) {
  constexpr int NB = BN / 32;              // n-fragments per wave
  __shared__ __align__(16) bf16_t lA[128 * 32];
  __shared__ __align__(16) bf16_t lB[BN * 32];
  const int tid = threadIdx.x;
  const int wave = tid >> 6, lane = tid & 63;
  const int r = lane & 15, kg = lane >> 4;
  const int bm = blockIdx.y * 128, bn = blockIdx.x * BN;
  const int wr = (wave >> 1) * 64, wc = (wave & 1) * (BN / 2);
  const bf16_t* Ab = A + (size_t)bm * K;
  const bf16_t* Wb = W + (size_t)bn * K;

  f32x4 acc[4][NB] = {};
  for (int k0 = 0; k0 < K; k0 += 32) {
    __syncthreads();
    {
      const int cb0 = (wave << 6);
      const int c0 = cb0 + lane;
      gld_lds16(Ab + (size_t)(c0 >> 2) * K + k0 + (c0 & 3) * 8, lA + cb0 * 8);
      const int cb1 = cb0 + 256;
      const int c1 = cb1 + lane;
      gld_lds16(Ab + (size_t)(c1 >> 2) * K + k0 + (c1 & 3) * 8, lA + cb1 * 8);
      if (BN == 128) {
        gld_lds16(Wb + (size_t)(c0 >> 2) * K + k0 + (c0 & 3) * 8, lB + cb0 * 8);
        gld_lds16(Wb + (size_t)(c1 >> 2) * K + k0 + (c1 & 3) * 8, lB + cb1 * 8);
      } else {
        gld_lds16(Wb + (size_t)(c0 >> 2) * K + k0 + (c0 & 3) * 8, lB + cb0 * 8);
      }
    }
    __syncthreads();
    bf16x8 af[4], bfr[NB];
    #pragma unroll
    for (int m = 0; m < 4; ++m)
      af[m] = *(const bf16x8*)&lA[(wr + m * 16 + r) * 32 + kg * 8];
    #pragma unroll
    for (int n = 0; n < NB; ++n)
      bfr[n] = *(const bf16x8*)&lB[(wc + n * 16 + r) * 32 + kg * 8];
    #pragma unroll
    for (int m = 0; m < 4; ++m)
      #pragma unroll
      for (int n = 0; n < NB; ++n)
        acc[m][n] = mfma16(af[m], bfr[n], acc[m][n]);
  }
  #pragma unroll
  for (int m = 0; m < 4; ++m) {
    const int row0 = bm + wr + m * 16 + kg * 4;
    #pragma unroll
    for (int n = 0; n < NB; ++n) {
      const int col = bn + wc + n * 16 + r;
      #pragma unroll
      for (int g2 = 0; g2 < 4; ++g2) {
        const size_t idx = (size_t)(row0 + g2) * N + col;
        const float v = acc[m][n][g2];
        if (MODE == 0) {
          outB[idx] = (bf16_t)v;
        } else if (MODE == 1) {
          outF[idx] = v + res[idx];
        } else {
          const float gf = (float)gate[idx];
          outB[idx] = (bf16_t)(v * gf / (1.f + __expf(-gf)));
        }
      }
    }
  }
}

// ---------------- RoPE on q,k from qkv rows ----------------
__global__ __launch_bounds__(256) void rope_kernel(const bf16_t* __restrict__ qkv,
                                                   bf16_t* __restrict__ q_r,
                                                   bf16_t* __restrict__ k_r,
                                                   const int* __restrict__ start_pos) {
  const int bs = blockIdx.x;             // b*S + s
  const int b = bs >> 11, s = bs & (S_ - 1);
  const float t = (float)(s + start_pos[0]);
  const bf16_t* rowp = qkv + (size_t)bs * 3072;
  #pragma unroll
  for (int i = 0; i < 4; ++i) {
    const int p = threadIdx.x + 256 * i;     // 0..1023
    const int mat = p >> 9;                  // 0=q, 1=k
    const int rem = p & 511;
    const int h = rem >> 5, d2 = rem & 31;
    const float freq = exp2f((float)d2 * -0.4152410118609203f);  // log2(10000)/32
    float sn, cs;
    sincosf(t * freq, &sn, &cs);
    const bf16x2 e2 = *(const bf16x2*)(rowp + mat * 1024 + h * 64 + 2 * d2);
    const float e = (float)e2[0], od = (float)e2[1];
    bf16x2 ov;
    ov[0] = (bf16_t)(e * cs - od * sn);
    ov[1] = (bf16_t)(e * sn + od * cs);
    bf16_t* dst = (mat ? k_r : q_r) + ((size_t)(b * NH + h) * S_ + s) * HD + 2 * d2;
    *(bf16x2*)dst = ov;
  }
}

// ---------------- V transpose: qkv v-part -> vt[bh][hd][s] ----------------
__global__ __launch_bounds__(256) void vtrans_kernel(const bf16_t* __restrict__ qkv,
                                                     bf16_t* __restrict__ vt) {
  const int bh = blockIdx.y, b = bh >> 4, h = bh & 15;
  const int s0 = blockIdx.x * 64;
  __shared__ bf16_t tile[64][65];
  #pragma unroll
  for (int i = 0; i < 16; ++i) {
    const int idx = threadIdx.x + 256 * i;    // 0..4095
    const int sl = idx >> 6, d = idx & 63;
    tile[sl][d] = qkv[(size_t)(b * S_ + s0 + sl) * 3072 + 2048 + h * 64 + d];
  }
  __syncthreads();
  #pragma unroll
  for (int i = 0; i < 16; ++i) {
    const int idx = threadIdx.x + 256 * i;
    const int dl = idx >> 6, sl = idx & 63;
    vt[((size_t)bh * HD + dl) * S_ + s0 + sl] = tile[sl][dl];
  }
}

// ---------------- causal flash attention, swapped-QK^T, no LDS, no P-shuffle --
// grid: (32, B*NH), 4 waves. Each wave owns ONE 16-row q-chunk:
//   qchunk = 127 - (blockIdx.x*4 + wave)   (LPT: longest chunks dispatch first)
// 4096 waves total -> 16 waves/CU (50% occupancy cap). KV blocks of 64.
// Swapped scores: lane(r,kg) holds score(k = kb+f*16+kg*4+g2, q = qbase+r).
// PV uses a permuted k<->slot bijection so each lane's own P values form the
// A-fragment (slot (kg,e<4) <-> k=fa*32+kg*4+e; slot (kg,e>=4) <-> +16), with
// V loaded at matching per-lane offsets. No cross-lane P movement.
__global__ __launch_bounds__(256) void attn_kernel(const bf16_t* __restrict__ qr,
                                                   const bf16_t* __restrict__ kr,
                                                   const bf16_t* __restrict__ vt,
                                                   bf16_t* __restrict__ out) {
  const int bh = blockIdx.y, b = bh >> 4, h = bh & 15;
  const int wave = threadIdx.x >> 6, lane = threadIdx.x & 63;
  const int r = lane & 15, kg = lane >> 4;
  const bf16_t* kb_p = kr + (size_t)bh * S_ * HD;
  const bf16_t* vb_p = vt + (size_t)bh * HD * S_;

  const int qchunk = 127 - (blockIdx.x * 4 + wave);
  const int qbase = qchunk * 16;
  const bf16_t* qp = qr + ((size_t)bh * S_ + qbase) * HD;
  const bf16x8 qf0 = *(const bf16x8*)&qp[r * HD + kg * 8];
  const bf16x8 qf1 = *(const bf16x8*)&qp[r * HD + 32 + kg * 8];
  f32x4 o[4] = {};                 // o[dblk][g2]: row q=kg*4+g2, col d=dblk*16+r
  float m = -1e30f, l = 0.f;       // for row q = qbase + r
  const int limit = qbase + 16;
  for (int kb = 0; kb < limit; kb += 64) {
    // ---- QK^T swapped: st[f] = K[kb+16f..+16] x Q^T ----
    f32x4 st[4];
    #pragma unroll
    for (int f = 0; f < 4; ++f) {
      const bf16_t* kp = kb_p + (size_t)(kb + f * 16 + r) * HD;
      f32x4 z = {};
      z = mfma16(*(const bf16x8*)&kp[kg * 8], qf0, z);
      z = mfma16(*(const bf16x8*)&kp[32 + kg * 8], qf1, z);
      st[f] = z;
    }
    // ---- mask + scale; lane holds 16 k-values for row q=qbase+r ----
    float sc[4][4];
    float mx = -1e30f;
    #pragma unroll
    for (int f = 0; f < 4; ++f)
      #pragma unroll
      for (int g2 = 0; g2 < 4; ++g2) {
        const int k = kb + f * 16 + kg * 4 + g2;
        const float v = (k <= qbase + r) ? st[f][g2] * 0.125f : -1e30f;
        sc[f][g2] = v;
        mx = fmaxf(mx, v);
      }
    mx = fmaxf(mx, __shfl_xor(mx, 16));
    mx = fmaxf(mx, __shfl_xor(mx, 32));
    const float nm = fmaxf(m, mx);
    const float alpha = __expf(m - nm);
    m = nm;
    float psum = 0.f;
    float pe[4][4];
    #pragma unroll
    for (int f = 0; f < 4; ++f)
      #pragma unroll
      for (int g2 = 0; g2 < 4; ++g2) {
        const float p = __expf(sc[f][g2] - nm);
        pe[f][g2] = p;
        psum += p;
      }
    psum += __shfl_xor(psum, 16);
    psum += __shfl_xor(psum, 32);
    l = l * alpha + psum;
    // ---- build PV A-fragments from the lane's OWN P values ----
    bf16x8 PA[2];
    #pragma unroll
    for (int fa = 0; fa < 2; ++fa) {
      bf16x8 v;
      #pragma unroll
      for (int j = 0; j < 4; ++j) v[j] = (bf16_t)pe[2 * fa][j];
      #pragma unroll
      for (int j = 0; j < 4; ++j) v[4 + j] = (bf16_t)pe[2 * fa + 1][j];
      PA[fa] = v;
    }
    // ---- rescale o by per-row alpha (rows q = kg*4+g2) ----
    float av[4];
    #pragma unroll
    for (int g2 = 0; g2 < 4; ++g2) av[g2] = __shfl(alpha, kg * 4 + g2);
    #pragma unroll
    for (int dblk = 0; dblk < 4; ++dblk)
      #pragma unroll
      for (int g2 = 0; g2 < 4; ++g2) o[dblk][g2] *= av[g2];
    // ---- PV: B-fragment slots match PA's k<->slot bijection ----
    #pragma unroll
    for (int dblk = 0; dblk < 4; ++dblk) {
      const bf16_t* vp = vb_p + (size_t)(dblk * 16 + r) * S_ + kb;
      #pragma unroll
      for (int fa = 0; fa < 2; ++fa) {
        union { bf16x8 v; bf16x4 hf[2]; } bv;
        bv.hf[0] = *(const bf16x4*)&vp[fa * 32 + kg * 4];
        bv.hf[1] = *(const bf16x4*)&vp[fa * 32 + 16 + kg * 4];
        o[dblk] = mfma16(PA[fa], bv.v, o[dblk]);
      }
    }
  }
  // ---- epilogue: divide by per-row l, write ----
  float lv[4];
  #pragma unroll
  for (int g2 = 0; g2 < 4; ++g2) lv[g2] = __shfl(l, kg * 4 + g2);
  #pragma unroll
  for (int dblk = 0; dblk < 4; ++dblk)
    #pragma unroll
    for (int g2 = 0; g2 < 4; ++g2) {
      const int srow = qbase + kg * 4 + g2;
      out[(size_t)(b * S_ + srow) * D_ + h * HD + dblk * 16 + r] =
          (bf16_t)(o[dblk][g2] / lv[g2]);
    }
}

// ---------------- host ----------------
extern "C" void kernel_launch(void* const* d_in, const int* in_sizes, int n_in,
                              void* d_out, int out_size, void* d_ws, size_t ws_size,
                              hipStream_t stream) {
  const float* x     = (const float*)d_in[0];
  const int*   sp    = (const int*)d_in[1];
  const float* n1w   = (const float*)d_in[2];
  const float* wqkv  = (const float*)d_in[3];
  const float* wo    = (const float*)d_in[4];
  const float* n2w   = (const float*)d_in[5];
  const float* wgate = (const float*)d_in[6];
  const float* wup   = (const float*)d_in[7];
  const float* wdown = (const float*)d_in[8];

  char* p = (char*)d_ws;
  bf16_t* wqkv_b = (bf16_t*)p; p += (size_t)3 * D_ * D_ * 2;      // 6 MB
  bf16_t* wo_b   = (bf16_t*)p; p += (size_t)D_ * D_ * 2;          // 2 MB
  bf16_t* wg_b   = (bf16_t*)p; p += (size_t)FF * D_ * 2;          // 8 MB
  bf16_t* wu_b   = (bf16_t*)p; p += (size_t)FF * D_ * 2;
  bf16_t* wd_b   = (bf16_t*)p; p += (size_t)FF * D_ * 2;
  bf16_t* xn     = (bf16_t*)p; p += (size_t)NTOK * D_ * 2;        // 8 MB
  float*  x1     = (float*)p;  p += (size_t)NTOK * D_ * 4;        // 16 MB
  char* pool = p;
  // phase A
  bf16_t* qkv    = (bf16_t*)(pool);
  bf16_t* q_r    = (bf16_t*)(pool + (size_t)25165824);
  bf16_t* k_r    = (bf16_t*)(pool + (size_t)33554432);
  bf16_t* v_t    = (bf16_t*)(pool + (size_t)41943040);
  bf16_t* attn_o = (bf16_t*)(pool + (size_t)50331648);
  // phase B (overlaps dead phase-A buffers)
  bf16_t* gbuf   = (bf16_t*)(pool);
  bf16_t* hbuf   = (bf16_t*)(pool + (size_t)33554432);

  cvt_kernel<<<dim3(1024), dim3(256), 0, stream>>>(wqkv,  wqkv_b, 3 * D_ * D_ / 4);
  cvt_kernel<<<dim3(1024), dim3(256), 0, stream>>>(wo,    wo_b,   D_ * D_ / 4);
  cvt_kernel<<<dim3(1024), dim3(256), 0, stream>>>(wgate, wg_b,   FF * D_ / 4);
  cvt_kernel<<<dim3(1024), dim3(256), 0, stream>>>(wup,   wu_b,   FF * D_ / 4);
  cvt_kernel<<<dim3(1024), dim3(256), 0, stream>>>(wdown, wd_b,   FF * D_ / 4);

  rmsnorm_kernel<<<dim3(NTOK), dim3(256), 0, stream>>>(x, n1w, xn);

  gemm_kernel<0,128><<<dim3(3 * D_ / 128, NTOK / 128), dim3(256), 0, stream>>>(
      xn, wqkv_b, NTOK, 3 * D_, D_, nullptr, qkv, nullptr, nullptr);

  rope_kernel<<<dim3(NTOK), dim3(256), 0, stream>>>(qkv, q_r, k_r, sp);
  vtrans_kernel<<<dim3(S_ / 64, B_ * NH), dim3(256), 0, stream>>>(qkv, v_t);

  attn_kernel<<<dim3(32, B_ * NH), dim3(256), 0, stream>>>(q_r, k_r, v_t, attn_o);

  gemm_kernel<1,64><<<dim3(D_ / 64, NTOK / 128), dim3(256), 0, stream>>>(
      attn_o, wo_b, NTOK, D_, D_, x1, nullptr, x, nullptr);

  rmsnorm_kernel<<<dim3(NTOK), dim3(256), 0, stream>>>(x1, n2w, xn);

  gemm_kernel<0,128><<<dim3(FF / 128, NTOK / 128), dim3(256), 0, stream>>>(
      xn, wg_b, NTOK, FF, D_, nullptr, gbuf, nullptr, nullptr);

  gemm_kernel<2,128><<<dim3(FF / 128, NTOK / 128), dim3(256), 0, stream>>>(
      xn, wu_b, NTOK, FF, D_, nullptr, hbuf, nullptr, gbuf);

  gemm_kernel<1,64><<<dim3(D_ / 64, NTOK / 128), dim3(256), 0, stream>>>(
      hbuf, wd_b, NTOK, D_, FF, (float*)d_out, nullptr, x1, nullptr);
}

// Round 6
// 593.919 us; speedup vs baseline: 1.2701x; 1.2701x over previous
//
#include <hip/hip_runtime.h>
#include <math.h>

typedef __bf16 bf16_t;
typedef __bf16 bf16x2 __attribute__((ext_vector_type(2)));
typedef __bf16 bf16x4 __attribute__((ext_vector_type(4)));
typedef __bf16 bf16x8 __attribute__((ext_vector_type(8)));
typedef float f32x4 __attribute__((ext_vector_type(4)));

#define B_ 2
#define S_ 2048
#define D_ 1024
#define NH 16
#define HD 64
#define FF 4096
#define NTOK (B_*S_)   // 4096 rows

__device__ __forceinline__ f32x4 mfma16(bf16x8 a, bf16x8 b, f32x4 c) {
  return __builtin_amdgcn_mfma_f32_16x16x32_bf16(a, b, c, 0, 0, 0);
}

__device__ __forceinline__ void gld_lds16(const bf16_t* g, bf16_t* l) {
  __builtin_amdgcn_global_load_lds(
      (const __attribute__((address_space(1))) void*)g,
      (__attribute__((address_space(3))) void*)l, 16, 0, 0);
}

// ---------------- fp32 -> bf16 convert ----------------
__global__ __launch_bounds__(256) void cvt_kernel(const float* __restrict__ in,
                                                  bf16_t* __restrict__ o, int n4) {
  int i = blockIdx.x * 256 + threadIdx.x;
  const int stride = gridDim.x * 256;
  for (; i < n4; i += stride) {
    float4 v = ((const float4*)in)[i];
    bf16x4 ov;
    ov[0] = (bf16_t)v.x; ov[1] = (bf16_t)v.y; ov[2] = (bf16_t)v.z; ov[3] = (bf16_t)v.w;
    ((bf16x4*)o)[i] = ov;
  }
}

// ---------------- RMSNorm (fp32 in, bf16 out) ----------------
__global__ __launch_bounds__(256) void rmsnorm_kernel(const float* __restrict__ x,
                                                      const float* __restrict__ w,
                                                      bf16_t* __restrict__ o) {
  const int row = blockIdx.x;
  const float4 v = ((const float4*)(x + (size_t)row * D_))[threadIdx.x];
  float s = v.x*v.x + v.y*v.y + v.z*v.z + v.w*v.w;
  #pragma unroll
  for (int d = 32; d; d >>= 1) s += __shfl_down(s, d);
  __shared__ float acc[4];
  if ((threadIdx.x & 63) == 0) acc[threadIdx.x >> 6] = s;
  __syncthreads();
  const float scale = rsqrtf((acc[0] + acc[1] + acc[2] + acc[3]) * (1.f / D_) + 1e-6f);
  const float4 wv = ((const float4*)w)[threadIdx.x];
  bf16x4 ov;
  ov[0] = (bf16_t)(v.x * scale * wv.x);
  ov[1] = (bf16_t)(v.y * scale * wv.y);
  ov[2] = (bf16_t)(v.z * scale * wv.z);
  ov[3] = (bf16_t)(v.w * scale * wv.w);
  ((bf16x4*)(o + (size_t)row * D_))[threadIdx.x] = ov;
}

// ---------------- GEMM: C(MxN) = A(MxK,bf16) @ W(NxK,bf16)^T ----------------
// BM=128 fixed; BN in {64,128}. 4 waves.
template<int MODE, int BN>
__global__ __launch_bounds__(256) void gemm_kernel(
    const bf16_t* __restrict__ A, const bf16_t* __restrict__ W,
    int M, int N, int K,
    float* __restrict__ outF, bf16_t* __restrict__ outB,
    const float* __restrict__ res, const bf16_t* __restrict__ gate) {
  constexpr int NB = BN / 32;              // n-fragments per wave
  __shared__ __align__(16) bf16_t lA[128 * 32];
  __shared__ __align__(16) bf16_t lB[BN * 32];
  const int tid = threadIdx.x;
  const int wave = tid >> 6, lane = tid & 63;
  const int r = lane & 15, kg = lane >> 4;
  const int bm = blockIdx.y * 128, bn = blockIdx.x * BN;
  const int wr = (wave >> 1) * 64, wc = (wave & 1) * (BN / 2);
  const bf16_t* Ab = A + (size_t)bm * K;
  const bf16_t* Wb = W + (size_t)bn * K;

  f32x4 acc[4][NB] = {};
  for (int k0 = 0; k0 < K; k0 += 32) {
    __syncthreads();
    {
      const int cb0 = (wave << 6);
      const int c0 = cb0 + lane;
      gld_lds16(Ab + (size_t)(c0 >> 2) * K + k0 + (c0 & 3) * 8, lA + cb0 * 8);
      const int cb1 = cb0 + 256;
      const int c1 = cb1 + lane;
      gld_lds16(Ab + (size_t)(c1 >> 2) * K + k0 + (c1 & 3) * 8, lA + cb1 * 8);
      if (BN == 128) {
        gld_lds16(Wb + (size_t)(c0 >> 2) * K + k0 + (c0 & 3) * 8, lB + cb0 * 8);
        gld_lds16(Wb + (size_t)(c1 >> 2) * K + k0 + (c1 & 3) * 8, lB + cb1 * 8);
      } else {
        gld_lds16(Wb + (size_t)(c0 >> 2) * K + k0 + (c0 & 3) * 8, lB + cb0 * 8);
      }
    }
    __syncthreads();
    bf16x8 af[4], bfr[NB];
    #pragma unroll
    for (int m = 0; m < 4; ++m)
      af[m] = *(const bf16x8*)&lA[(wr + m * 16 + r) * 32 + kg * 8];
    #pragma unroll
    for (int n = 0; n < NB; ++n)
      bfr[n] = *(const bf16x8*)&lB[(wc + n * 16 + r) * 32 + kg * 8];
    #pragma unroll
    for (int m = 0; m < 4; ++m)
      #pragma unroll
      for (int n = 0; n < NB; ++n)
        acc[m][n] = mfma16(af[m], bfr[n], acc[m][n]);
  }
  #pragma unroll
  for (int m = 0; m < 4; ++m) {
    const int row0 = bm + wr + m * 16 + kg * 4;
    #pragma unroll
    for (int n = 0; n < NB; ++n) {
      const int col = bn + wc + n * 16 + r;
      #pragma unroll
      for (int g2 = 0; g2 < 4; ++g2) {
        const size_t idx = (size_t)(row0 + g2) * N + col;
        const float v = acc[m][n][g2];
        if (MODE == 0) {
          outB[idx] = (bf16_t)v;
        } else if (MODE == 1) {
          outF[idx] = v + res[idx];
        } else {
          const float gf = (float)gate[idx];
          outB[idx] = (bf16_t)(v * gf / (1.f + __expf(-gf)));
        }
      }
    }
  }
}

// ---------------- RoPE on q,k from qkv rows ----------------
__global__ __launch_bounds__(256) void rope_kernel(const bf16_t* __restrict__ qkv,
                                                   bf16_t* __restrict__ q_r,
                                                   bf16_t* __restrict__ k_r,
                                                   const int* __restrict__ start_pos) {
  const int bs = blockIdx.x;             // b*S + s
  const int b = bs >> 11, s = bs & (S_ - 1);
  const float t = (float)(s + start_pos[0]);
  const bf16_t* rowp = qkv + (size_t)bs * 3072;
  #pragma unroll
  for (int i = 0; i < 4; ++i) {
    const int p = threadIdx.x + 256 * i;     // 0..1023
    const int mat = p >> 9;                  // 0=q, 1=k
    const int rem = p & 511;
    const int h = rem >> 5, d2 = rem & 31;
    const float freq = exp2f((float)d2 * -0.4152410118609203f);  // log2(10000)/32
    float sn, cs;
    sincosf(t * freq, &sn, &cs);
    const bf16x2 e2 = *(const bf16x2*)(rowp + mat * 1024 + h * 64 + 2 * d2);
    const float e = (float)e2[0], od = (float)e2[1];
    bf16x2 ov;
    ov[0] = (bf16_t)(e * cs - od * sn);
    ov[1] = (bf16_t)(e * sn + od * cs);
    bf16_t* dst = (mat ? k_r : q_r) + ((size_t)(b * NH + h) * S_ + s) * HD + 2 * d2;
    *(bf16x2*)dst = ov;
  }
}

// ---------------- V transpose: qkv v-part -> vt[bh][hd][s] ----------------
__global__ __launch_bounds__(256) void vtrans_kernel(const bf16_t* __restrict__ qkv,
                                                     bf16_t* __restrict__ vt) {
  const int bh = blockIdx.y, b = bh >> 4, h = bh & 15;
  const int s0 = blockIdx.x * 64;
  __shared__ bf16_t tile[64][65];
  #pragma unroll
  for (int i = 0; i < 16; ++i) {
    const int idx = threadIdx.x + 256 * i;    // 0..4095
    const int sl = idx >> 6, d = idx & 63;
    tile[sl][d] = qkv[(size_t)(b * S_ + s0 + sl) * 3072 + 2048 + h * 64 + d];
  }
  __syncthreads();
  #pragma unroll
  for (int i = 0; i < 16; ++i) {
    const int idx = threadIdx.x + 256 * i;
    const int dl = idx >> 6, sl = idx & 63;
    vt[((size_t)bh * HD + dl) * S_ + s0 + sl] = tile[sl][dl];
  }
}

// ---------------- causal flash attention: paired chunks + KV-split ----------
// grid: (32, B*NH), 4 waves. Pair p = blockIdx.x*2 + (wave>>1), sub = wave&1.
// The two sub-waves of a pair process chunks A=p (16 rows) and B=127-p, each
// taking alternating 64-wide KV blocks (kb = sub*64, step 128) with private
// online-softmax state; partials merge via LDS (flash-decoding combine).
// Uniform ~16.5 trips/wave, 4096 waves -> 16 waves/CU.
// Swapped scores: lane(r,kg) holds score(k = kb+f*16+kg*4+g2, q = qbase+r).
// PV uses the permuted k<->slot bijection (lane-local P, no cross-lane moves).
__global__ __launch_bounds__(256, 4) void attn_kernel(const bf16_t* __restrict__ qr,
                                                      const bf16_t* __restrict__ kr,
                                                      const bf16_t* __restrict__ vt,
                                                      bf16_t* __restrict__ out) {
  const int bh = blockIdx.y, b = bh >> 4, h = bh & 15;
  const int wave = threadIdx.x >> 6, lane = threadIdx.x & 63;
  const int pl = wave >> 1, sub = wave & 1;
  const int r = lane & 15, kg = lane >> 4;
  const int pairIdx = blockIdx.x * 2 + pl;          // 0..63
  const bf16_t* kb_p = kr + (size_t)bh * S_ * HD;
  const bf16_t* vb_p = vt + (size_t)bh * HD * S_;

  __shared__ __align__(16) f32x4 lo[2][4][64];
  __shared__ float lm[2][64], ll[2][64];

  // run one chunk's KV-half; accumulates into o/m/l
  auto run_chunk = [&](int qbase, f32x4* o, float& m, float& l) {
    const bf16_t* qp = qr + ((size_t)bh * S_ + qbase) * HD;
    const bf16x8 qf0 = *(const bf16x8*)&qp[r * HD + kg * 8];
    const bf16x8 qf1 = *(const bf16x8*)&qp[r * HD + 32 + kg * 8];
    const int limit = qbase + 16;
    for (int kb = sub * 64; kb < limit; kb += 128) {
      f32x4 st[4];
      #pragma unroll
      for (int f = 0; f < 4; ++f) {
        const bf16_t* kp = kb_p + (size_t)(kb + f * 16 + r) * HD;
        f32x4 z = {};
        z = mfma16(*(const bf16x8*)&kp[kg * 8], qf0, z);
        z = mfma16(*(const bf16x8*)&kp[32 + kg * 8], qf1, z);
        st[f] = z;
      }
      float sc[4][4];
      float mx = -1e30f;
      #pragma unroll
      for (int f = 0; f < 4; ++f)
        #pragma unroll
        for (int g2 = 0; g2 < 4; ++g2) {
          const int k = kb + f * 16 + kg * 4 + g2;
          const float v = (k <= qbase + r) ? st[f][g2] * 0.125f : -1e30f;
          sc[f][g2] = v;
          mx = fmaxf(mx, v);
        }
      mx = fmaxf(mx, __shfl_xor(mx, 16));
      mx = fmaxf(mx, __shfl_xor(mx, 32));
      const float nm = fmaxf(m, mx);
      const float alpha = __expf(m - nm);
      m = nm;
      float psum = 0.f;
      float pe[4][4];
      #pragma unroll
      for (int f = 0; f < 4; ++f)
        #pragma unroll
        for (int g2 = 0; g2 < 4; ++g2) {
          const float p = __expf(sc[f][g2] - nm);
          pe[f][g2] = p;
          psum += p;
        }
      psum += __shfl_xor(psum, 16);
      psum += __shfl_xor(psum, 32);
      l = l * alpha + psum;
      bf16x8 PA[2];
      #pragma unroll
      for (int fa = 0; fa < 2; ++fa) {
        bf16x8 v;
        #pragma unroll
        for (int j = 0; j < 4; ++j) v[j] = (bf16_t)pe[2 * fa][j];
        #pragma unroll
        for (int j = 0; j < 4; ++j) v[4 + j] = (bf16_t)pe[2 * fa + 1][j];
        PA[fa] = v;
      }
      float av[4];
      #pragma unroll
      for (int g2 = 0; g2 < 4; ++g2) av[g2] = __shfl(alpha, kg * 4 + g2);
      #pragma unroll
      for (int dblk = 0; dblk < 4; ++dblk)
        #pragma unroll
        for (int g2 = 0; g2 < 4; ++g2) o[dblk][g2] *= av[g2];
      #pragma unroll
      for (int dblk = 0; dblk < 4; ++dblk) {
        const bf16_t* vp = vb_p + (size_t)(dblk * 16 + r) * S_ + kb;
        #pragma unroll
        for (int fa = 0; fa < 2; ++fa) {
          union { bf16x8 v; bf16x4 hf[2]; } bv;
          bv.hf[0] = *(const bf16x4*)&vp[fa * 32 + kg * 4];
          bv.hf[1] = *(const bf16x4*)&vp[fa * 32 + 16 + kg * 4];
          o[dblk] = mfma16(PA[fa], bv.v, o[dblk]);
        }
      }
    }
  };

  auto write_partial = [&](const f32x4* o, float m, float l) {
    #pragma unroll
    for (int dblk = 0; dblk < 4; ++dblk) lo[pl][dblk][lane] = o[dblk];
    lm[pl][lane] = m;
    ll[pl][lane] = l;
  };

  // merge own partial with LDS partial, finalize rows of this chunk
  auto finalize = [&](int qbase, const f32x4* o, float m, float l) {
    const float m1 = lm[pl][lane], l1 = ll[pl][lane];
    const float ms = fmaxf(m, m1);
    const float a0 = __expf(m - ms), a1 = __expf(m1 - ms);
    const float lt = l * a0 + l1 * a1;
    float av0[4], av1[4], lv[4];
    #pragma unroll
    for (int g2 = 0; g2 < 4; ++g2) {
      av0[g2] = __shfl(a0, kg * 4 + g2);
      av1[g2] = __shfl(a1, kg * 4 + g2);
      lv[g2]  = __shfl(lt, kg * 4 + g2);
    }
    #pragma unroll
    for (int dblk = 0; dblk < 4; ++dblk) {
      const f32x4 o1 = lo[pl][dblk][lane];
      #pragma unroll
      for (int g2 = 0; g2 < 4; ++g2) {
        const int srow = qbase + kg * 4 + g2;
        out[(size_t)(b * S_ + srow) * D_ + h * HD + dblk * 16 + r] =
            (bf16_t)((o[dblk][g2] * av0[g2] + o1[g2] * av1[g2]) / lv[g2]);
      }
    }
  };

  // ---- chunk A = pairIdx ----
  {
    const int qbase = pairIdx * 16;
    f32x4 o[4] = {};
    float m = -1e30f, l = 0.f;
    run_chunk(qbase, o, m, l);
    if (sub == 1) write_partial(o, m, l);
    __syncthreads();
    if (sub == 0) finalize(qbase, o, m, l);
  }
  // ---- chunk B = 127 - pairIdx ----
  {
    const int qbase = (127 - pairIdx) * 16;
    f32x4 o[4] = {};
    float m = -1e30f, l = 0.f;
    run_chunk(qbase, o, m, l);
    if (sub == 0) write_partial(o, m, l);
    __syncthreads();
    if (sub == 1) finalize(qbase, o, m, l);
  }
}

// ---------------- host ----------------
extern "C" void kernel_launch(void* const* d_in, const int* in_sizes, int n_in,
                              void* d_out, int out_size, void* d_ws, size_t ws_size,
                              hipStream_t stream) {
  const float* x     = (const float*)d_in[0];
  const int*   sp    = (const int*)d_in[1];
  const float* n1w   = (const float*)d_in[2];
  const float* wqkv  = (const float*)d_in[3];
  const float* wo    = (const float*)d_in[4];
  const float* n2w   = (const float*)d_in[5];
  const float* wgate = (const float*)d_in[6];
  const float* wup   = (const float*)d_in[7];
  const float* wdown = (const float*)d_in[8];

  char* p = (char*)d_ws;
  bf16_t* wqkv_b = (bf16_t*)p; p += (size_t)3 * D_ * D_ * 2;      // 6 MB
  bf16_t* wo_b   = (bf16_t*)p; p += (size_t)D_ * D_ * 2;          // 2 MB
  bf16_t* wg_b   = (bf16_t*)p; p += (size_t)FF * D_ * 2;          // 8 MB
  bf16_t* wu_b   = (bf16_t*)p; p += (size_t)FF * D_ * 2;
  bf16_t* wd_b   = (bf16_t*)p; p += (size_t)FF * D_ * 2;
  bf16_t* xn     = (bf16_t*)p; p += (size_t)NTOK * D_ * 2;        // 8 MB
  float*  x1     = (float*)p;  p += (size_t)NTOK * D_ * 4;        // 16 MB
  char* pool = p;
  // phase A
  bf16_t* qkv    = (bf16_t*)(pool);
  bf16_t* q_r    = (bf16_t*)(pool + (size_t)25165824);
  bf16_t* k_r    = (bf16_t*)(pool + (size_t)33554432);
  bf16_t* v_t    = (bf16_t*)(pool + (size_t)41943040);
  bf16_t* attn_o = (bf16_t*)(pool + (size_t)50331648);
  // phase B (overlaps dead phase-A buffers)
  bf16_t* gbuf   = (bf16_t*)(pool);
  bf16_t* hbuf   = (bf16_t*)(pool + (size_t)33554432);

  cvt_kernel<<<dim3(1024), dim3(256), 0, stream>>>(wqkv,  wqkv_b, 3 * D_ * D_ / 4);
  cvt_kernel<<<dim3(1024), dim3(256), 0, stream>>>(wo,    wo_b,   D_ * D_ / 4);
  cvt_kernel<<<dim3(1024), dim3(256), 0, stream>>>(wgate, wg_b,   FF * D_ / 4);
  cvt_kernel<<<dim3(1024), dim3(256), 0, stream>>>(wup,   wu_b,   FF * D_ / 4);
  cvt_kernel<<<dim3(1024), dim3(256), 0, stream>>>(wdown, wd_b,   FF * D_ / 4);

  rmsnorm_kernel<<<dim3(NTOK), dim3(256), 0, stream>>>(x, n1w, xn);

  gemm_kernel<0,128><<<dim3(3 * D_ / 128, NTOK / 128), dim3(256), 0, stream>>>(
      xn, wqkv_b, NTOK, 3 * D_, D_, nullptr, qkv, nullptr, nullptr);

  rope_kernel<<<dim3(NTOK), dim3(256), 0, stream>>>(qkv, q_r, k_r, sp);
  vtrans_kernel<<<dim3(S_ / 64, B_ * NH), dim3(256), 0, stream>>>(qkv, v_t);

  attn_kernel<<<dim3(32, B_ * NH), dim3(256), 0, stream>>>(q_r, k_r, v_t, attn_o);

  gemm_kernel<1,64><<<dim3(D_ / 64, NTOK / 128), dim3(256), 0, stream>>>(
      attn_o, wo_b, NTOK, D_, D_, x1, nullptr, x, nullptr);

  rmsnorm_kernel<<<dim3(NTOK), dim3(256), 0, stream>>>(x1, n2w, xn);

  gemm_kernel<0,128><<<dim3(FF / 128, NTOK / 128), dim3(256), 0, stream>>>(
      xn, wg_b, NTOK, FF, D_, nullptr, gbuf, nullptr, nullptr);

  gemm_kernel<2,128><<<dim3(FF / 128, NTOK / 128), dim3(256), 0, stream>>>(
      xn, wu_b, NTOK, FF, D_, nullptr, hbuf, nullptr, gbuf);

  gemm_kernel<1,64><<<dim3(D_ / 64, NTOK / 128), dim3(256), 0, stream>>>(
      hbuf, wd_b, NTOK, D_, FF, (float*)d_out, nullptr, x1, nullptr);
}

// Round 7
// 556.335 us; speedup vs baseline: 1.3559x; 1.0676x over previous
//
#include <hip/hip_runtime.h>
#include <math.h>

typedef __bf16 bf16_t;
typedef __bf16 bf16x2 __attribute__((ext_vector_type(2)));
typedef __bf16 bf16x4 __attribute__((ext_vector_type(4)));
typedef __bf16 bf16x8 __attribute__((ext_vector_type(8)));
typedef float f32x4 __attribute__((ext_vector_type(4)));

#define B_ 2
#define S_ 2048
#define D_ 1024
#define NH 16
#define HD 64
#define FF 4096
#define NTOK (B_*S_)   // 4096 rows

__device__ __forceinline__ f32x4 mfma16(bf16x8 a, bf16x8 b, f32x4 c) {
  return __builtin_amdgcn_mfma_f32_16x16x32_bf16(a, b, c, 0, 0, 0);
}

__device__ __forceinline__ void gld_lds16(const bf16_t* g, bf16_t* l) {
  __builtin_amdgcn_global_load_lds(
      (const __attribute__((address_space(1))) void*)g,
      (__attribute__((address_space(3))) void*)l, 16, 0, 0);
}

// ---------------- fp32 -> bf16 convert: all 5 weight tensors in one launch --
__global__ __launch_bounds__(256) void cvt5_kernel(
    const float* __restrict__ p0, const float* __restrict__ p1,
    const float* __restrict__ p2, const float* __restrict__ p3,
    const float* __restrict__ p4,
    bf16_t* __restrict__ o0, bf16_t* __restrict__ o1, bf16_t* __restrict__ o2,
    bf16_t* __restrict__ o3, bf16_t* __restrict__ o4) {
  // float4 counts: wqkv 786432, wo 262144, wg/wu/wd 1048576 each
  int i = blockIdx.x * 256 + threadIdx.x;
  const int stride = gridDim.x * 256;
  const int n = 4194304;
  for (; i < n; i += stride) {
    const float* src; bf16_t* dst; int j = i;
    if (j < 786432) { src = p0; dst = o0; }
    else {
      j -= 786432;
      if (j < 262144) { src = p1; dst = o1; }
      else {
        j -= 262144;
        if (j < 1048576) { src = p2; dst = o2; }
        else {
          j -= 1048576;
          if (j < 1048576) { src = p3; dst = o3; }
          else { j -= 1048576; src = p4; dst = o4; }
        }
      }
    }
    float4 v = ((const float4*)src)[j];
    bf16x4 ov;
    ov[0] = (bf16_t)v.x; ov[1] = (bf16_t)v.y; ov[2] = (bf16_t)v.z; ov[3] = (bf16_t)v.w;
    ((bf16x4*)dst)[j] = ov;
  }
}

// ---------------- RMSNorm (fp32 in, bf16 out) ----------------
__global__ __launch_bounds__(256) void rmsnorm_kernel(const float* __restrict__ x,
                                                      const float* __restrict__ w,
                                                      bf16_t* __restrict__ o) {
  const int row = blockIdx.x;
  const float4 v = ((const float4*)(x + (size_t)row * D_))[threadIdx.x];
  float s = v.x*v.x + v.y*v.y + v.z*v.z + v.w*v.w;
  #pragma unroll
  for (int d = 32; d; d >>= 1) s += __shfl_down(s, d);
  __shared__ float acc[4];
  if ((threadIdx.x & 63) == 0) acc[threadIdx.x >> 6] = s;
  __syncthreads();
  const float scale = rsqrtf((acc[0] + acc[1] + acc[2] + acc[3]) * (1.f / D_) + 1e-6f);
  const float4 wv = ((const float4*)w)[threadIdx.x];
  bf16x4 ov;
  ov[0] = (bf16_t)(v.x * scale * wv.x);
  ov[1] = (bf16_t)(v.y * scale * wv.y);
  ov[2] = (bf16_t)(v.z * scale * wv.z);
  ov[3] = (bf16_t)(v.w * scale * wv.w);
  ((bf16x4*)(o + (size_t)row * D_))[threadIdx.x] = ov;
}

// ---------------- GEMM: C(MxN) = A(MxK,bf16) @ W(NxK,bf16)^T ----------------
// 2-phase double-buffered staging (T3-minimum): stage tile t+1 before the
// MFMA work of tile t; one vmcnt(0)+barrier per K-step.
template<int MODE, int BN>
__global__ __launch_bounds__(256) void gemm_kernel(
    const bf16_t* __restrict__ A, const bf16_t* __restrict__ W,
    int M, int N, int K,
    float* __restrict__ outF, bf16_t* __restrict__ outB,
    const float* __restrict__ res, const bf16_t* __restrict__ gate) {
  constexpr int NB = BN / 32;              // n-fragments per wave
  __shared__ __align__(16) bf16_t lA[2][128 * 32];
  __shared__ __align__(16) bf16_t lB[2][BN * 32];
  const int tid = threadIdx.x;
  const int wave = tid >> 6, lane = tid & 63;
  const int r = lane & 15, kg = lane >> 4;
  const int bm = blockIdx.y * 128, bn = blockIdx.x * BN;
  const int wr = (wave >> 1) * 64, wc = (wave & 1) * (BN / 2);
  const bf16_t* Ab = A + (size_t)bm * K;
  const bf16_t* Wb = W + (size_t)bn * K;

  auto stage = [&](int buf, int k0) {
    const int cb0 = (wave << 6);
    const int c0 = cb0 + lane;
    gld_lds16(Ab + (size_t)(c0 >> 2) * K + k0 + (c0 & 3) * 8, lA[buf] + cb0 * 8);
    const int cb1 = cb0 + 256;
    const int c1 = cb1 + lane;
    gld_lds16(Ab + (size_t)(c1 >> 2) * K + k0 + (c1 & 3) * 8, lA[buf] + cb1 * 8);
    gld_lds16(Wb + (size_t)(c0 >> 2) * K + k0 + (c0 & 3) * 8, lB[buf] + cb0 * 8);
    if (BN == 128)
      gld_lds16(Wb + (size_t)(c1 >> 2) * K + k0 + (c1 & 3) * 8, lB[buf] + cb1 * 8);
  };

  f32x4 acc[4][NB] = {};
  stage(0, 0);
  asm volatile("s_waitcnt vmcnt(0)" ::: "memory");
  __syncthreads();
  int cur = 0;
  for (int k0 = 0; k0 < K; k0 += 32) {
    if (k0 + 32 < K) stage(cur ^ 1, k0 + 32);
    const bf16_t* cA = lA[cur];
    const bf16_t* cB = lB[cur];
    bf16x8 af[4], bfr[NB];
    #pragma unroll
    for (int m = 0; m < 4; ++m)
      af[m] = *(const bf16x8*)&cA[(wr + m * 16 + r) * 32 + kg * 8];
    #pragma unroll
    for (int n = 0; n < NB; ++n)
      bfr[n] = *(const bf16x8*)&cB[(wc + n * 16 + r) * 32 + kg * 8];
    #pragma unroll
    for (int m = 0; m < 4; ++m)
      #pragma unroll
      for (int n = 0; n < NB; ++n)
        acc[m][n] = mfma16(af[m], bfr[n], acc[m][n]);
    asm volatile("s_waitcnt vmcnt(0)" ::: "memory");
    __syncthreads();
    cur ^= 1;
  }
  #pragma unroll
  for (int m = 0; m < 4; ++m) {
    const int row0 = bm + wr + m * 16 + kg * 4;
    #pragma unroll
    for (int n = 0; n < NB; ++n) {
      const int col = bn + wc + n * 16 + r;
      #pragma unroll
      for (int g2 = 0; g2 < 4; ++g2) {
        const size_t idx = (size_t)(row0 + g2) * N + col;
        const float v = acc[m][n][g2];
        if (MODE == 0) {
          outB[idx] = (bf16_t)v;
        } else if (MODE == 1) {
          outF[idx] = v + res[idx];
        } else {
          const float gf = (float)gate[idx];
          outB[idx] = (bf16_t)(v * gf / (1.f + __expf(-gf)));
        }
      }
    }
  }
}

// ---------------- RoPE on q,k from qkv rows ----------------
// q additionally scaled by 0.125*log2(e) so attention scores are in the
// log2 domain with the 1/sqrt(HD) factor folded in (attn uses exp2).
__global__ __launch_bounds__(256) void rope_kernel(const bf16_t* __restrict__ qkv,
                                                   bf16_t* __restrict__ q_r,
                                                   bf16_t* __restrict__ k_r,
                                                   const int* __restrict__ start_pos) {
  const int bs = blockIdx.x;             // b*S + s
  const int b = bs >> 11, s = bs & (S_ - 1);
  const float t = (float)(s + start_pos[0]);
  const bf16_t* rowp = qkv + (size_t)bs * 3072;
  #pragma unroll
  for (int i = 0; i < 4; ++i) {
    const int p = threadIdx.x + 256 * i;     // 0..1023
    const int mat = p >> 9;                  // 0=q, 1=k
    const int rem = p & 511;
    const int h = rem >> 5, d2 = rem & 31;
    const float freq = exp2f((float)d2 * -0.4152410118609203f);  // log2(10000)/32
    float sn, cs;
    sincosf(t * freq, &sn, &cs);
    const float qs = mat ? 1.0f : 0.18033688011112042f;  // 0.125*log2(e)
    const bf16x2 e2 = *(const bf16x2*)(rowp + mat * 1024 + h * 64 + 2 * d2);
    const float e = (float)e2[0], od = (float)e2[1];
    bf16x2 ov;
    ov[0] = (bf16_t)((e * cs - od * sn) * qs);
    ov[1] = (bf16_t)((e * sn + od * cs) * qs);
    bf16_t* dst = (mat ? k_r : q_r) + ((size_t)(b * NH + h) * S_ + s) * HD + 2 * d2;
    *(bf16x2*)dst = ov;
  }
}

// ---------------- V transpose: qkv v-part -> vt[bh][hd][s] ----------------
__global__ __launch_bounds__(256) void vtrans_kernel(const bf16_t* __restrict__ qkv,
                                                     bf16_t* __restrict__ vt) {
  const int bh = blockIdx.y, b = bh >> 4, h = bh & 15;
  const int s0 = blockIdx.x * 64;
  __shared__ bf16_t tile[64][65];
  #pragma unroll
  for (int i = 0; i < 16; ++i) {
    const int idx = threadIdx.x + 256 * i;    // 0..4095
    const int sl = idx >> 6, d = idx & 63;
    tile[sl][d] = qkv[(size_t)(b * S_ + s0 + sl) * 3072 + 2048 + h * 64 + d];
  }
  __syncthreads();
  #pragma unroll
  for (int i = 0; i < 16; ++i) {
    const int idx = threadIdx.x + 256 * i;
    const int dl = idx >> 6, sl = idx & 63;
    vt[((size_t)bh * HD + dl) * S_ + s0 + sl] = tile[sl][dl];
  }
}

// ---------------- causal flash attention: paired chunks + KV-split ----------
// grid: (32, B*NH)=(32,32); XCD-clustered remap keeps all 32 x-blocks of one
// bh on one XCD (4 bh per XCD -> 2 MB K/V per L2). Pair p = bx*2 + (wave>>1),
// sub = wave&1; sub-waves split KV blocks (kb = sub*64, step 128) with
// private online-softmax state, merged via LDS (flash-decoding combine).
// Scores arrive pre-scaled to log2 domain (rope folds 0.125*log2e into q).
// Interior KV blocks skip masking (exactly one masked block per chunk);
// defer-max (T13, THR=8) skips the o-rescale on most blocks.
__global__ __launch_bounds__(256, 4) void attn_kernel(const bf16_t* __restrict__ qr,
                                                      const bf16_t* __restrict__ kr,
                                                      const bf16_t* __restrict__ vt,
                                                      bf16_t* __restrict__ out) {
  const int lid = blockIdx.x + 32 * blockIdx.y;   // 0..1023
  const int xcd = lid & 7, slot = lid >> 3;       // 128 slots per xcd
  const int bh = xcd * 4 + (slot >> 5);           // 4 bh per xcd
  const int bx = slot & 31;                       // 0..31
  const int b = bh >> 4, h = bh & 15;
  const int wave = threadIdx.x >> 6, lane = threadIdx.x & 63;
  const int pl = wave >> 1, sub = wave & 1;
  const int r = lane & 15, kg = lane >> 4;
  const int pairIdx = bx * 2 + pl;                // 0..63
  const bf16_t* kb_p = kr + (size_t)bh * S_ * HD;
  const bf16_t* vb_p = vt + (size_t)bh * HD * S_;

  __shared__ __align__(16) f32x4 lo[2][4][64];
  __shared__ float lm[2][64], ll[2][64];

  auto kv_block = [&](int kb, int qbase, const bf16x8& qf0, const bf16x8& qf1,
                      f32x4* o, float& m, float& l, bool masked) {
    f32x4 st[4];
    #pragma unroll
    for (int f = 0; f < 4; ++f) {
      const bf16_t* kp = kb_p + (size_t)(kb + f * 16 + r) * HD;
      f32x4 z = {};
      z = mfma16(*(const bf16x8*)&kp[kg * 8], qf0, z);
      z = mfma16(*(const bf16x8*)&kp[32 + kg * 8], qf1, z);
      st[f] = z;
    }
    float sc[4][4];
    float mx = -1e30f;
    #pragma unroll
    for (int f = 0; f < 4; ++f)
      #pragma unroll
      for (int g2 = 0; g2 < 4; ++g2) {
        float v = st[f][g2];
        if (masked) {
          const int k = kb + f * 16 + kg * 4 + g2;
          v = (k <= qbase + r) ? v : -1e30f;
        }
        sc[f][g2] = v;
        mx = fmaxf(mx, v);
      }
    mx = fmaxf(mx, __shfl_xor(mx, 16));
    mx = fmaxf(mx, __shfl_xor(mx, 32));
    float alpha = 1.f;
    const bool need = !__all(mx - m <= 8.f);
    if (need) {
      const float nm = fmaxf(m, mx);
      alpha = exp2f(m - nm);
      m = nm;
    }
    float psum = 0.f;
    float pe[4][4];
    #pragma unroll
    for (int f = 0; f < 4; ++f)
      #pragma unroll
      for (int g2 = 0; g2 < 4; ++g2) {
        const float p = exp2f(sc[f][g2] - m);
        pe[f][g2] = p;
        psum += p;
      }
    psum += __shfl_xor(psum, 16);
    psum += __shfl_xor(psum, 32);
    l = l * alpha + psum;
    bf16x8 PA[2];
    #pragma unroll
    for (int fa = 0; fa < 2; ++fa) {
      bf16x8 v;
      #pragma unroll
      for (int j = 0; j < 4; ++j) v[j] = (bf16_t)pe[2 * fa][j];
      #pragma unroll
      for (int j = 0; j < 4; ++j) v[4 + j] = (bf16_t)pe[2 * fa + 1][j];
      PA[fa] = v;
    }
    if (need) {
      float av[4];
      #pragma unroll
      for (int g2 = 0; g2 < 4; ++g2) av[g2] = __shfl(alpha, kg * 4 + g2);
      #pragma unroll
      for (int dblk = 0; dblk < 4; ++dblk)
        #pragma unroll
        for (int g2 = 0; g2 < 4; ++g2) o[dblk][g2] *= av[g2];
    }
    #pragma unroll
    for (int dblk = 0; dblk < 4; ++dblk) {
      const bf16_t* vp = vb_p + (size_t)(dblk * 16 + r) * S_ + kb;
      #pragma unroll
      for (int fa = 0; fa < 2; ++fa) {
        union { bf16x8 v; bf16x4 hf[2]; } bv;
        bv.hf[0] = *(const bf16x4*)&vp[fa * 32 + kg * 4];
        bv.hf[1] = *(const bf16x4*)&vp[fa * 32 + 16 + kg * 4];
        o[dblk] = mfma16(PA[fa], bv.v, o[dblk]);
      }
    }
  };

  auto run_chunk = [&](int qbase, f32x4* o, float& m, float& l) {
    const bf16_t* qp = qr + ((size_t)bh * S_ + qbase) * HD;
    const bf16x8 qf0 = *(const bf16x8*)&qp[r * HD + kg * 8];
    const bf16x8 qf1 = *(const bf16x8*)&qp[r * HD + 32 + kg * 8];
    int kb = sub * 64;
    for (; kb + 64 <= qbase; kb += 128)
      kv_block(kb, qbase, qf0, qf1, o, m, l, false);
    if (kb < qbase + 16)
      kv_block(kb, qbase, qf0, qf1, o, m, l, true);   // exactly one masked block
  };

  auto write_partial = [&](const f32x4* o, float m, float l) {
    #pragma unroll
    for (int dblk = 0; dblk < 4; ++dblk) lo[pl][dblk][lane] = o[dblk];
    lm[pl][lane] = m;
    ll[pl][lane] = l;
  };

  auto finalize = [&](int qbase, const f32x4* o, float m, float l) {
    const float m1 = lm[pl][lane], l1 = ll[pl][lane];
    const float ms = fmaxf(m, m1);
    const float a0 = exp2f(m - ms), a1 = exp2f(m1 - ms);
    const float lt = l * a0 + l1 * a1;
    float av0[4], av1[4], lv[4];
    #pragma unroll
    for (int g2 = 0; g2 < 4; ++g2) {
      av0[g2] = __shfl(a0, kg * 4 + g2);
      av1[g2] = __shfl(a1, kg * 4 + g2);
      lv[g2]  = __shfl(lt, kg * 4 + g2);
    }
    #pragma unroll
    for (int dblk = 0; dblk < 4; ++dblk) {
      const f32x4 o1 = lo[pl][dblk][lane];
      #pragma unroll
      for (int g2 = 0; g2 < 4; ++g2) {
        const int srow = qbase + kg * 4 + g2;
        out[(size_t)(b * S_ + srow) * D_ + h * HD + dblk * 16 + r] =
            (bf16_t)((o[dblk][g2] * av0[g2] + o1[g2] * av1[g2]) / lv[g2]);
      }
    }
  };

  // ---- chunk A = pairIdx ----
  {
    const int qbase = pairIdx * 16;
    f32x4 o[4] = {};
    float m = -1e30f, l = 0.f;
    run_chunk(qbase, o, m, l);
    if (sub == 1) write_partial(o, m, l);
    __syncthreads();
    if (sub == 0) finalize(qbase, o, m, l);
  }
  // ---- chunk B = 127 - pairIdx ----
  {
    const int qbase = (127 - pairIdx) * 16;
    f32x4 o[4] = {};
    float m = -1e30f, l = 0.f;
    run_chunk(qbase, o, m, l);
    if (sub == 0) write_partial(o, m, l);
    __syncthreads();
    if (sub == 1) finalize(qbase, o, m, l);
  }
}

// ---------------- host ----------------
extern "C" void kernel_launch(void* const* d_in, const int* in_sizes, int n_in,
                              void* d_out, int out_size, void* d_ws, size_t ws_size,
                              hipStream_t stream) {
  const float* x     = (const float*)d_in[0];
  const int*   sp    = (const int*)d_in[1];
  const float* n1w   = (const float*)d_in[2];
  const float* wqkv  = (const float*)d_in[3];
  const float* wo    = (const float*)d_in[4];
  const float* n2w   = (const float*)d_in[5];
  const float* wgate = (const float*)d_in[6];
  const float* wup   = (const float*)d_in[7];
  const float* wdown = (const float*)d_in[8];

  char* p = (char*)d_ws;
  bf16_t* wqkv_b = (bf16_t*)p; p += (size_t)3 * D_ * D_ * 2;      // 6 MB
  bf16_t* wo_b   = (bf16_t*)p; p += (size_t)D_ * D_ * 2;          // 2 MB
  bf16_t* wg_b   = (bf16_t*)p; p += (size_t)FF * D_ * 2;          // 8 MB
  bf16_t* wu_b   = (bf16_t*)p; p += (size_t)FF * D_ * 2;
  bf16_t* wd_b   = (bf16_t*)p; p += (size_t)FF * D_ * 2;
  bf16_t* xn     = (bf16_t*)p; p += (size_t)NTOK * D_ * 2;        // 8 MB
  float*  x1     = (float*)p;  p += (size_t)NTOK * D_ * 4;        // 16 MB
  char* pool = p;
  // phase A
  bf16_t* qkv    = (bf16_t*)(pool);
  bf16_t* q_r    = (bf16_t*)(pool + (size_t)25165824);
  bf16_t* k_r    = (bf16_t*)(pool + (size_t)33554432);
  bf16_t* v_t    = (bf16_t*)(pool + (size_t)41943040);
  bf16_t* attn_o = (bf16_t*)(pool + (size_t)50331648);
  // phase B (overlaps dead phase-A buffers)
  bf16_t* gbuf   = (bf16_t*)(pool);
  bf16_t* hbuf   = (bf16_t*)(pool + (size_t)33554432);

  cvt5_kernel<<<dim3(2048), dim3(256), 0, stream>>>(
      wqkv, wo, wgate, wup, wdown, wqkv_b, wo_b, wg_b, wu_b, wd_b);

  rmsnorm_kernel<<<dim3(NTOK), dim3(256), 0, stream>>>(x, n1w, xn);

  gemm_kernel<0,128><<<dim3(3 * D_ / 128, NTOK / 128), dim3(256), 0, stream>>>(
      xn, wqkv_b, NTOK, 3 * D_, D_, nullptr, qkv, nullptr, nullptr);

  rope_kernel<<<dim3(NTOK), dim3(256), 0, stream>>>(qkv, q_r, k_r, sp);
  vtrans_kernel<<<dim3(S_ / 64, B_ * NH), dim3(256), 0, stream>>>(qkv, v_t);

  attn_kernel<<<dim3(32, B_ * NH), dim3(256), 0, stream>>>(q_r, k_r, v_t, attn_o);

  gemm_kernel<1,64><<<dim3(D_ / 64, NTOK / 128), dim3(256), 0, stream>>>(
      attn_o, wo_b, NTOK, D_, D_, x1, nullptr, x, nullptr);

  rmsnorm_kernel<<<dim3(NTOK), dim3(256), 0, stream>>>(x1, n2w, xn);

  gemm_kernel<0,128><<<dim3(FF / 128, NTOK / 128), dim3(256), 0, stream>>>(
      xn, wg_b, NTOK, FF, D_, nullptr, gbuf, nullptr, nullptr);

  gemm_kernel<2,128><<<dim3(FF / 128, NTOK / 128), dim3(256), 0, stream>>>(
      xn, wu_b, NTOK, FF, D_, nullptr, hbuf, nullptr, gbuf);

  gemm_kernel<1,64><<<dim3(D_ / 64, NTOK / 128), dim3(256), 0, stream>>>(
      hbuf, wd_b, NTOK, D_, FF, (float*)d_out, nullptr, x1, nullptr);
}